// Round 6
// baseline (995.797 us; speedup 1.0000x reference)
//
#include <hip/hip_runtime.h>
#include <hip/hip_bf16.h>
#include <stdint.h>

typedef unsigned short u16;
typedef __attribute__((ext_vector_type(8))) short short8;
typedef __attribute__((ext_vector_type(8))) __bf16 bf16x8;
typedef __attribute__((ext_vector_type(4))) float f32x4;

#define DEV static __device__ __forceinline__

DEV float bf2f(u16 u) { uint32_t i = ((uint32_t)u) << 16; float f; __builtin_memcpy(&f, &i, 4); return f; }
DEV u16 f2bf(float f) {
    uint32_t i; __builtin_memcpy(&i, &f, 4);
    uint32_t r = i + 0x7FFFu + ((i >> 16) & 1u);
    return (u16)(r >> 16);
}
DEV float lo16f(uint32_t u) { uint32_t i = u << 16; float f; __builtin_memcpy(&f, &i, 4); return f; }
DEV float hi16f(uint32_t u) { uint32_t i = u & 0xFFFF0000u; float f; __builtin_memcpy(&f, &i, 4); return f; }
DEV uint32_t pack2(float a, float b) { return (uint32_t)f2bf(a) | ((uint32_t)f2bf(b) << 16); }
DEV float lrelu(float x) { return x >= 0.f ? x : 0.2f * x; }

#define BSH 7   // 128 nodes per bucket

// ---------------- x -> bf16 pre-convert ----------------
__global__ __launch_bounds__(256) void k_cvt(const float* __restrict__ in, u16* __restrict__ out, int n4) {
    int i = blockIdx.x * 256 + threadIdx.x;
    if (i < n4) {
        float4 v = ((const float4*)in)[i];
        ushort4 o;
        o.x = f2bf(v.x); o.y = f2bf(v.y); o.z = f2bf(v.z); o.w = f2bf(v.w);
        ((ushort4*)out)[i] = o;
    }
}

// ---------------- CSR build ----------------
__global__ void k_count(const int* __restrict__ dst, int* __restrict__ deg, int E) {
    int e = blockIdx.x * 256 + threadIdx.x;
    if (e < E) atomicAdd(&deg[dst[e]], 1);
}

__global__ void k_scanpart(const int* __restrict__ deg, int* __restrict__ bsum, int n, int N) {
    __shared__ int buf[1024];
    int tid = threadIdx.x;
    int i = blockIdx.x * 1024 + tid;
    int v = (i < N) ? deg[i] : 0;
    buf[tid] = v; __syncthreads();
    for (int d = 512; d > 0; d >>= 1) {
        if (tid < d) buf[tid] += buf[tid + d];
        __syncthreads();
    }
    if (tid == 0) bsum[blockIdx.x] = buf[0];
}

__global__ void k_scanbsum(int* bsum, int nb) {
    if (threadIdx.x == 0) {
        int run = 0;
        for (int b = 0; b < nb; ++b) { int t = bsum[b]; bsum[b] = run; run += t; }
    }
}

__global__ void k_scanfinal(const int* __restrict__ deg, const int* __restrict__ bsum,
                            int* __restrict__ off, int* __restrict__ cursor, int n, int N) {
    __shared__ int buf[1024];
    int tid = threadIdx.x;
    int i = blockIdx.x * 1024 + tid;
    int v = (i < N) ? deg[i] : 0;
    buf[tid] = v; __syncthreads();
    for (int d = 1; d < 1024; d <<= 1) {
        int t = (tid >= d) ? buf[tid - d] : 0;
        __syncthreads();
        buf[tid] += t;
        __syncthreads();
    }
    int ex = buf[tid] - v + bsum[blockIdx.x];
    if (i < n) { off[i] = ex; if (i < N) cursor[i] = ex; }
}

// bucket cursors init: bucket b covers nodes [b*128, (b+1)*128), edges at [off[b*128], ...)
__global__ void k_binit(const int* __restrict__ off, int* __restrict__ bcur, int NB, int N) {
    int b = blockIdx.x * 256 + threadIdx.x;
    if (b < NB) { int n = b << BSH; bcur[b] = off[n < N ? n : N]; }
}

// pass A: bin (src,dst) pairs into dst-bucket-contiguous staging
__global__ void k_binpass(const int* __restrict__ src, const int* __restrict__ dst,
                          int* __restrict__ bcur, int2* __restrict__ stage, int E) {
    int e = blockIdx.x * 256 + threadIdx.x;
    if (e < E) {
        int d = dst[e];
        int p = atomicAdd(&bcur[d >> BSH], 1);
        stage[p] = make_int2(src[e], d);
    }
}

// pass B: exact scatter within buckets (write locality: ~9KB region per bucket)
__global__ void k_scatter2(const int2* __restrict__ stage, int* __restrict__ cursor,
                           int* __restrict__ srt, int E) {
    int e = blockIdx.x * 256 + threadIdx.x;
    if (e < E) {
        int2 sd = stage[e];
        int p = atomicAdd(&cursor[sd.y], 1);
        srt[p] = sd.x;
    }
}

// ---------------- GEMM: out[N,M](bf16) = concat(A1[N,K1],A2[N,K2])(bf16) @ W[K,M](f32) ----------------
__global__ __launch_bounds__(256) void gemm_k(const u16* __restrict__ A1, int K1,
                                              const u16* __restrict__ A2, int K2,
                                              const float* __restrict__ W, int M,
                                              u16* __restrict__ out, int N) {
    __shared__ u16 wt[64][328];
    __shared__ u16 As[64][40];
    const int K = K1 + K2;
    const int tid = threadIdx.x;
    const int n0 = blockIdx.x * 64;
    const int cb = blockIdx.y * 64;

    for (int idx = tid; idx < K * 64; idx += 256) {
        int k = idx >> 6, m = idx & 63;
        wt[m][k] = f2bf(W[(size_t)k * M + cb + m]);
    }

    const int wv = tid >> 6, lane = tid & 63;
    const int quad = lane >> 4, r = lane & 15;
    f32x4 acc[4];
#pragma unroll
    for (int ct = 0; ct < 4; ++ct) acc[ct] = (f32x4){0.f, 0.f, 0.f, 0.f};

    const int row = tid >> 2, seg = tid & 3;
    const int gl = n0 + row;

    for (int k0 = 0; k0 < K; k0 += 32) {
        int4 v = {0, 0, 0, 0};
        if (gl < N) {
            const u16* base = (k0 < K1) ? (A1 + (size_t)gl * K1 + k0)
                                        : (A2 + (size_t)gl * K2 + (k0 - K1));
            v = *(const int4*)(base + seg * 8);
        }
        *(int4*)&As[row][seg * 8] = v;
        __syncthreads();
        bf16x8 a = __builtin_bit_cast(bf16x8, *(const short8*)&As[wv * 16 + r][quad * 8]);
#pragma unroll
        for (int ct = 0; ct < 4; ++ct) {
            bf16x8 b = __builtin_bit_cast(bf16x8, *(const short8*)&wt[ct * 16 + r][k0 + quad * 8]);
            acc[ct] = __builtin_amdgcn_mfma_f32_16x16x32_bf16(a, b, acc[ct], 0, 0, 0);
        }
        __syncthreads();
    }

#pragma unroll
    for (int ct = 0; ct < 4; ++ct)
#pragma unroll
        for (int rg = 0; rg < 4; ++rg) {
            int grow = n0 + wv * 16 + quad * 4 + rg;
            if (grow < N) out[(size_t)grow * M + cb + ct * 16 + r] = f2bf(acc[ct][rg]);
        }
}

// ---------------- attention coefficients: a_src/a_dst [N,8] fp32 ----------------
__global__ __launch_bounds__(256) void acomp8(const u16* __restrict__ g,
                                              const float* __restrict__ ats, const float* __restrict__ atd,
                                              float* __restrict__ a_src, float* __restrict__ a_dst, int N) {
    int lane = threadIdx.x & 63;
    int node = blockIdx.x * 4 + (threadIdx.x >> 6);
    if (node >= N) return;
    float val = bf2f(g[(size_t)node * 64 + lane]);
    float ps = val * ats[lane];
    float pd = val * atd[lane];
#pragma unroll
    for (int d = 1; d < 8; d <<= 1) { ps += __shfl_xor(ps, d); pd += __shfl_xor(pd, d); }
    if ((lane & 7) == 0) {
        a_src[node * 8 + (lane >> 3)] = ps;
        a_dst[node * 8 + (lane >> 3)] = pd;
    }
}

__global__ __launch_bounds__(256) void acomp16(const u16* __restrict__ g,
                                               const float* __restrict__ ats, const float* __restrict__ atd,
                                               float* __restrict__ a_src, float* __restrict__ a_dst, int N) {
    int lane = threadIdx.x & 63;
    int node = blockIdx.x * 4 + (threadIdx.x >> 6);
    if (node >= N) return;
    float v0 = bf2f(g[(size_t)node * 128 + lane]);
    float v1 = bf2f(g[(size_t)node * 128 + lane + 64]);
    float ps0 = v0 * ats[lane],      pd0 = v0 * atd[lane];
    float ps1 = v1 * ats[lane + 64], pd1 = v1 * atd[lane + 64];
#pragma unroll
    for (int d = 1; d < 16; d <<= 1) {
        ps0 += __shfl_xor(ps0, d); pd0 += __shfl_xor(pd0, d);
        ps1 += __shfl_xor(ps1, d); pd1 += __shfl_xor(pd1, d);
    }
    if ((lane & 15) == 0) {
        int hd = lane >> 4;
        a_src[node * 8 + hd] = ps0;     a_dst[node * 8 + hd] = pd0;
        a_src[node * 8 + hd + 4] = ps1; a_dst[node * 8 + hd + 4] = pd1;
    }
}

// ---------------- layer 1/2 aggregation: 2 nodes/wave, 2 channels/lane ----------------
// lane32 handles channels (2*lane32, 2*lane32+1); head of pair = lane32>>2.
__global__ __launch_bounds__(256) void agg12(const u16* __restrict__ g,
                                             const float* __restrict__ a_src, const float* __restrict__ a_dst,
                                             const int* __restrict__ off, const int* __restrict__ srt,
                                             const float* __restrict__ bias, const float* __restrict__ pslope,
                                             u16* __restrict__ hout, int N) {
    int tid = threadIdx.x;
    int lane32 = tid & 31;
    int node = blockIdx.x * 8 + (tid >> 5);
    int nd = node < N ? node : N - 1;
    int hd = lane32 >> 2;          // head for accumulation layout
    int hw = lane32 & 7;           // head for weight-compute layout
    int e4 = lane32 >> 3;          // edge slot (0..3) for weight-compute layout
    float ad_acc = a_dst[nd * 8 + hd];
    float ad_w   = a_dst[nd * 8 + hw];
    float ws = __expf(lrelu(a_src[nd * 8 + hd] + ad_acc));   // self loop
    uint32_t gs = *(const uint32_t*)(g + (size_t)nd * 64 + lane32 * 2);
    float s = ws;
    float acc0 = ws * lo16f(gs), acc1 = ws * hi16f(gs);
    int jb = off[nd], je = off[nd + 1];
    int addrH = (tid & 32) * 4;        // byte addr of half-wave base lane
    int addrW = addrH + hd * 4;
    for (int j = jb; j < je; j += 4) {
        int cnt = je - j;              // uniform per half
        int jj = j + e4;
        int idx = srt[jj < je ? jj : (je - 1)];
        float w = __expf(lrelu(a_src[idx * 8 + hw] + ad_w));
        int wi = __builtin_bit_cast(int, w);
#pragma unroll
        for (int t = 0; t < 4; ++t) {
            int srcv = __builtin_amdgcn_ds_bpermute(addrH + t * 32, idx);
            int wvi  = __builtin_amdgcn_ds_bpermute(addrW + t * 32, wi);
            float wv = (t < cnt) ? __builtin_bit_cast(float, wvi) : 0.f;
            uint32_t gv = *(const uint32_t*)(g + (size_t)srcv * 64 + lane32 * 2);
            s += wv;
            acc0 += wv * lo16f(gv);
            acc1 += wv * hi16f(gv);
        }
    }
    float r = 1.f / (s + 1e-16f);
    float2 bv = *(const float2*)(bias + lane32 * 2);
    float p = pslope[0];
    float v0 = acc0 * r + bv.x; v0 = v0 >= 0.f ? v0 : p * v0;
    float v1 = acc1 * r + bv.y; v1 = v1 >= 0.f ? v1 : p * v1;
    if (node < N) *(uint32_t*)(hout + (size_t)node * 64 + lane32 * 2) = pack2(v0, v1);
}

// ---------------- layer 3 aggregation + head-mean + bias + log_softmax ----------------
// lane handles channels (2*lane mod 16-pair): head = lane>>3, cpair = lane&7, ch = head*16 + cpair*2 (+1)
__global__ __launch_bounds__(256) void agg3(const u16* __restrict__ g,
                                            const float* __restrict__ a_src, const float* __restrict__ a_dst,
                                            const int* __restrict__ off, const int* __restrict__ srt,
                                            const float* __restrict__ b3, float* __restrict__ out, int N) {
    int tid = threadIdx.x;
    int lane = tid & 63;
    int node = blockIdx.x * 4 + (tid >> 6);
    int nd = node < N ? node : N - 1;
    int hd = lane >> 3;       // head for accumulation (== e8 of weight layout)
    int hw = lane & 7;        // head for weight layout
    float ad_acc = a_dst[nd * 8 + hd];
    float ad_w   = a_dst[nd * 8 + hw];
    float ws = __expf(lrelu(a_src[nd * 8 + hd] + ad_acc));
    uint32_t gs = *(const uint32_t*)(g + (size_t)nd * 128 + lane * 2);
    float s = ws;
    float acc0 = ws * lo16f(gs), acc1 = ws * hi16f(gs);
    int jb = off[nd], je = off[nd + 1];
    int addrW = hd * 4;
    for (int j = jb; j < je; j += 8) {
        int cnt = je - j;
        int jj = j + hd;      // e8 == hd
        int idx = srt[jj < je ? jj : (je - 1)];
        float w = __expf(lrelu(a_src[idx * 8 + hw] + ad_w));
        int wi = __builtin_bit_cast(int, w);
#pragma unroll
        for (int t = 0; t < 8; ++t) {
            int srcv = __builtin_amdgcn_readlane(idx, t * 8);
            int wvi  = __builtin_amdgcn_ds_bpermute(addrW + t * 32, wi);
            float wv = (t < cnt) ? __builtin_bit_cast(float, wvi) : 0.f;
            uint32_t gv = *(const uint32_t*)(g + (size_t)srcv * 128 + lane * 2);
            s += wv;
            acc0 += wv * lo16f(gv);
            acc1 += wv * hi16f(gv);
        }
    }
    float r = 1.f / (s + 1e-16f);
    float v0 = acc0 * r, v1 = acc1 * r;
    // sum over 8 heads (lanes differing in bits 3..5)
    v0 += __shfl_xor(v0, 8);  v1 += __shfl_xor(v1, 8);
    v0 += __shfl_xor(v0, 16); v1 += __shfl_xor(v1, 16);
    v0 += __shfl_xor(v0, 32); v1 += __shfl_xor(v1, 32);
    int c0 = (lane & 7) * 2;
    float2 bv = *(const float2*)(b3 + c0);
    float mean0 = v0 * 0.125f + bv.x, mean1 = v1 * 0.125f + bv.y;
    float m = fmaxf(mean0, mean1);
    m = fmaxf(m, __shfl_xor(m, 1)); m = fmaxf(m, __shfl_xor(m, 2)); m = fmaxf(m, __shfl_xor(m, 4));
    float se = __expf(mean0 - m) + __expf(mean1 - m);
    se += __shfl_xor(se, 1); se += __shfl_xor(se, 2); se += __shfl_xor(se, 4);
    float lg = __logf(se);
    if (node < N && lane < 8) {
        float2 o; o.x = mean0 - m - lg; o.y = mean1 - m - lg;
        *(float2*)(out + (size_t)node * 16 + c0) = o;
    }
}

// ---------------- launch ----------------
extern "C" void kernel_launch(void* const* d_in, const int* in_sizes, int n_in,
                              void* d_out, int out_size, void* d_ws, size_t ws_size,
                              hipStream_t stream) {
    (void)n_in; (void)out_size; (void)ws_size;
    const float* x  = (const float*)d_in[0];
    const int* ei   = (const int*)d_in[1];
    const float* W1 = (const float*)d_in[2];
    const float* as1 = (const float*)d_in[3];
    const float* ad1 = (const float*)d_in[4];
    const float* b1  = (const float*)d_in[5];
    const float* W2  = (const float*)d_in[6];
    const float* as2 = (const float*)d_in[7];
    const float* ad2 = (const float*)d_in[8];
    const float* b2  = (const float*)d_in[9];
    const float* W3  = (const float*)d_in[10];
    const float* as3 = (const float*)d_in[11];
    const float* ad3 = (const float*)d_in[12];
    const float* b3  = (const float*)d_in[13];
    const float* p1  = (const float*)d_in[14];
    const float* p2  = (const float*)d_in[15];
    const int N = in_sizes[0] / 256;
    const int E = in_sizes[1] / 2;
    const int NB = (N + (1 << BSH) - 1) >> BSH;

    char* ws = (char*)d_ws;
    size_t o = 0;
    auto alloc = [&](size_t bytes) { void* p = ws + o; o = (o + bytes + 255) & ~(size_t)255; return p; };
    int* deg    = (int*)alloc((size_t)N * 4);
    int* off    = (int*)alloc((size_t)(N + 1) * 4);
    int* cursor = (int*)alloc((size_t)N * 4);
    int* bsum   = (int*)alloc(4096);
    int* bcur   = (int*)alloc((size_t)NB * 4);
    int* srt    = (int*)alloc((size_t)E * 4);
    int2* stage = (int2*)alloc((size_t)E * 8);
    u16* xb     = (u16*)alloc((size_t)N * 256 * 2);
    u16* g      = (u16*)alloc((size_t)N * 128 * 2);
    float* a_src = (float*)alloc((size_t)N * 8 * 4);
    float* a_dst = (float*)alloc((size_t)N * 8 * 4);
    u16* h1     = (u16*)alloc((size_t)N * 64 * 2);
    u16* h2     = (u16*)alloc((size_t)N * 64 * 2);

    hipMemsetAsync(deg, 0, (size_t)N * 4, stream);
    int n4 = N * 256 / 4;
    k_cvt<<<(n4 + 255) / 256, 256, 0, stream>>>(x, xb, n4);
    int eb = (E + 255) / 256;
    k_count<<<eb, 256, 0, stream>>>(ei + E, deg, E);
    int nS = (N + 1 + 1023) / 1024;
    k_scanpart<<<nS, 1024, 0, stream>>>(deg, bsum, N + 1, N);
    k_scanbsum<<<1, 64, 0, stream>>>(bsum, nS);
    k_scanfinal<<<nS, 1024, 0, stream>>>(deg, bsum, off, cursor, N + 1, N);
    k_binit<<<(NB + 255) / 256, 256, 0, stream>>>(off, bcur, NB, N);
    k_binpass<<<eb, 256, 0, stream>>>(ei, ei + E, bcur, stage, E);
    k_scatter2<<<eb, 256, 0, stream>>>(stage, cursor, srt, E);

    int nb64 = (N + 63) / 64;
    int nb4 = (N + 3) / 4;
    int nb8 = (N + 7) / 8;

    // layer 1: x[N,256] @ W1[256,64]
    gemm_k<<<dim3(nb64, 1), 256, 0, stream>>>(xb, 256, (const u16*)nullptr, 0, W1, 64, g, N);
    acomp8<<<nb4, 256, 0, stream>>>(g, as1, ad1, a_src, a_dst, N);
    agg12<<<nb8, 256, 0, stream>>>(g, a_src, a_dst, off, srt, b1, p1, h1, N);

    // layer 2: concat(x, h1)[N,320] @ W2[320,64]
    gemm_k<<<dim3(nb64, 1), 256, 0, stream>>>(xb, 256, h1, 64, W2, 64, g, N);
    acomp8<<<nb4, 256, 0, stream>>>(g, as2, ad2, a_src, a_dst, N);
    agg12<<<nb8, 256, 0, stream>>>(g, a_src, a_dst, off, srt, b2, p2, h2, N);

    // layer 3: h2[N,64] @ W3[64,128], mean over heads + log_softmax
    gemm_k<<<dim3(nb64, 2), 256, 0, stream>>>(h2, 64, (const u16*)nullptr, 0, W3, 128, g, N);
    acomp16<<<nb4, 256, 0, stream>>>(g, as3, ad3, a_src, a_dst, N);
    agg3<<<nb4, 256, 0, stream>>>(g, a_src, a_dst, off, srt, b3, (float*)d_out, N);
}

// Round 8
// 706.519 us; speedup vs baseline: 1.4094x; 1.4094x over previous
//
#include <hip/hip_runtime.h>
#include <hip/hip_bf16.h>
#include <stdint.h>

typedef unsigned short u16;
typedef __attribute__((ext_vector_type(8))) short short8;
typedef __attribute__((ext_vector_type(8))) __bf16 bf16x8;
typedef __attribute__((ext_vector_type(4))) float f32x4;
typedef __attribute__((ext_vector_type(4))) float fv4;

#define DEV static __device__ __forceinline__

DEV float bf2f(u16 u) { uint32_t i = ((uint32_t)u) << 16; float f; __builtin_memcpy(&f, &i, 4); return f; }
DEV u16 f2bf(float f) {
    uint32_t i; __builtin_memcpy(&i, &f, 4);
    uint32_t r = i + 0x7FFFu + ((i >> 16) & 1u);
    return (u16)(r >> 16);
}
DEV float lo16f(uint32_t u) { uint32_t i = u << 16; float f; __builtin_memcpy(&f, &i, 4); return f; }
DEV float hi16f(uint32_t u) { uint32_t i = u & 0xFFFF0000u; float f; __builtin_memcpy(&f, &i, 4); return f; }
DEV uint32_t pack2(float a, float b) { return (uint32_t)f2bf(a) | ((uint32_t)f2bf(b) << 16); }
DEV float lrelu(float x) { return x >= 0.f ? x : 0.2f * x; }

// ---------------- x -> bf16 pre-convert ----------------
__global__ __launch_bounds__(256) void k_cvt(const float* __restrict__ in, u16* __restrict__ out, int n4) {
    int i = blockIdx.x * 256 + threadIdx.x;
    if (i < n4) {
        fv4 v = __builtin_nontemporal_load((const fv4*)in + i);
        ushort4 o;
        o.x = f2bf(v.x); o.y = f2bf(v.y); o.z = f2bf(v.z); o.w = f2bf(v.w);
        ((ushort4*)out)[i] = o;
    }
}

// ---------------- CSR build ----------------
__global__ void k_count(const int* __restrict__ dst, int* __restrict__ deg, int E) {
    int e = blockIdx.x * 256 + threadIdx.x;
    if (e < E) atomicAdd(&deg[dst[e]], 1);
}

__global__ void k_scanpart(const int* __restrict__ deg, int* __restrict__ bsum, int n, int N) {
    __shared__ int buf[1024];
    int tid = threadIdx.x;
    int i = blockIdx.x * 1024 + tid;
    int v = (i < N) ? deg[i] : 0;
    buf[tid] = v; __syncthreads();
    for (int d = 512; d > 0; d >>= 1) {
        if (tid < d) buf[tid] += buf[tid + d];
        __syncthreads();
    }
    if (tid == 0) bsum[blockIdx.x] = buf[0];
}

__global__ void k_scanbsum(int* bsum, int nb) {
    if (threadIdx.x == 0) {
        int run = 0;
        for (int b = 0; b < nb; ++b) { int t = bsum[b]; bsum[b] = run; run += t; }
    }
}

__global__ void k_scanfinal(const int* __restrict__ deg, const int* __restrict__ bsum,
                            int* __restrict__ off, int* __restrict__ cursor, int n, int N) {
    __shared__ int buf[1024];
    int tid = threadIdx.x;
    int i = blockIdx.x * 1024 + tid;
    int v = (i < N) ? deg[i] : 0;
    buf[tid] = v; __syncthreads();
    for (int d = 1; d < 1024; d <<= 1) {
        int t = (tid >= d) ? buf[tid - d] : 0;
        __syncthreads();
        buf[tid] += t;
        __syncthreads();
    }
    int ex = buf[tid] - v + bsum[blockIdx.x];
    if (i < n) { off[i] = ex; if (i < N) cursor[i] = ex; }
}

__global__ void k_scatter(const int* __restrict__ src, const int* __restrict__ dst,
                          int* __restrict__ cursor, int* __restrict__ srt, int E) {
    int e = blockIdx.x * 256 + threadIdx.x;
    if (e < E) {
        int p = atomicAdd(&cursor[dst[e]], 1);
        __builtin_nontemporal_store(src[e], srt + p);
    }
}

// ---------------- GEMM: out[N,M](bf16) = concat(A1[N,K1],A2[N,K2])(bf16) @ W[K,M](f32) ----------------
__global__ __launch_bounds__(256) void gemm_k(const u16* __restrict__ A1, int K1,
                                              const u16* __restrict__ A2, int K2,
                                              const float* __restrict__ W, int M,
                                              u16* __restrict__ out, int N) {
    __shared__ u16 wt[64][328];
    __shared__ u16 As[64][40];
    const int K = K1 + K2;
    const int tid = threadIdx.x;
    const int n0 = blockIdx.x * 64;
    const int cb = blockIdx.y * 64;

    for (int idx = tid; idx < K * 64; idx += 256) {
        int k = idx >> 6, m = idx & 63;
        wt[m][k] = f2bf(W[(size_t)k * M + cb + m]);
    }

    const int wv = tid >> 6, lane = tid & 63;
    const int quad = lane >> 4, r = lane & 15;
    f32x4 acc[4];
#pragma unroll
    for (int ct = 0; ct < 4; ++ct) acc[ct] = (f32x4){0.f, 0.f, 0.f, 0.f};

    const int row = tid >> 2, seg = tid & 3;
    const int gl = n0 + row;

    for (int k0 = 0; k0 < K; k0 += 32) {
        int4 v = {0, 0, 0, 0};
        if (gl < N) {
            const u16* base = (k0 < K1) ? (A1 + (size_t)gl * K1 + k0)
                                        : (A2 + (size_t)gl * K2 + (k0 - K1));
            v = *(const int4*)(base + seg * 8);
        }
        *(int4*)&As[row][seg * 8] = v;
        __syncthreads();
        bf16x8 a = __builtin_bit_cast(bf16x8, *(const short8*)&As[wv * 16 + r][quad * 8]);
#pragma unroll
        for (int ct = 0; ct < 4; ++ct) {
            bf16x8 b = __builtin_bit_cast(bf16x8, *(const short8*)&wt[ct * 16 + r][k0 + quad * 8]);
            acc[ct] = __builtin_amdgcn_mfma_f32_16x16x32_bf16(a, b, acc[ct], 0, 0, 0);
        }
        __syncthreads();
    }

#pragma unroll
    for (int ct = 0; ct < 4; ++ct)
#pragma unroll
        for (int rg = 0; rg < 4; ++rg) {
            int grow = n0 + wv * 16 + quad * 4 + rg;
            if (grow < N) out[(size_t)grow * M + cb + ct * 16 + r] = f2bf(acc[ct][rg]);
        }
}

// ---------------- attention coefficients: a_src/a_dst [N,8] fp32 ----------------
__global__ __launch_bounds__(256) void acomp8(const u16* __restrict__ g,
                                              const float* __restrict__ ats, const float* __restrict__ atd,
                                              float* __restrict__ a_src, float* __restrict__ a_dst, int N) {
    int lane = threadIdx.x & 63;
    int node = blockIdx.x * 4 + (threadIdx.x >> 6);
    if (node >= N) return;
    float val = bf2f(g[(size_t)node * 64 + lane]);
    float ps = val * ats[lane];
    float pd = val * atd[lane];
#pragma unroll
    for (int d = 1; d < 8; d <<= 1) { ps += __shfl_xor(ps, d); pd += __shfl_xor(pd, d); }
    if ((lane & 7) == 0) {
        a_src[node * 8 + (lane >> 3)] = ps;
        a_dst[node * 8 + (lane >> 3)] = pd;
    }
}

__global__ __launch_bounds__(256) void acomp16(const u16* __restrict__ g,
                                               const float* __restrict__ ats, const float* __restrict__ atd,
                                               float* __restrict__ a_src, float* __restrict__ a_dst, int N) {
    int lane = threadIdx.x & 63;
    int node = blockIdx.x * 4 + (threadIdx.x >> 6);
    if (node >= N) return;
    float v0 = bf2f(g[(size_t)node * 128 + lane]);
    float v1 = bf2f(g[(size_t)node * 128 + lane + 64]);
    float ps0 = v0 * ats[lane],      pd0 = v0 * atd[lane];
    float ps1 = v1 * ats[lane + 64], pd1 = v1 * atd[lane + 64];
#pragma unroll
    for (int d = 1; d < 16; d <<= 1) {
        ps0 += __shfl_xor(ps0, d); pd0 += __shfl_xor(pd0, d);
        ps1 += __shfl_xor(ps1, d); pd1 += __shfl_xor(pd1, d);
    }
    if ((lane & 15) == 0) {
        int hd = lane >> 4;
        a_src[node * 8 + hd] = ps0;     a_dst[node * 8 + hd] = pd0;
        a_src[node * 8 + hd + 4] = ps1; a_dst[node * 8 + hd + 4] = pd1;
    }
}

// ---------------- layer 1/2 aggregation: 2 nodes/wave, 2 channels/lane ----------------
__global__ __launch_bounds__(256) void agg12(const u16* __restrict__ g,
                                             const float* __restrict__ a_src, const float* __restrict__ a_dst,
                                             const int* __restrict__ off, const int* __restrict__ srt,
                                             const float* __restrict__ bias, const float* __restrict__ pslope,
                                             u16* __restrict__ hout, int N) {
    int tid = threadIdx.x;
    int lane32 = tid & 31;
    int node = blockIdx.x * 8 + (tid >> 5);
    int nd = node < N ? node : N - 1;
    int hd = lane32 >> 2;          // head for accumulation layout
    int hw = lane32 & 7;           // head for weight-compute layout
    int e4 = lane32 >> 3;          // edge slot (0..3) for weight-compute layout
    float ad_acc = a_dst[nd * 8 + hd];
    float ad_w   = a_dst[nd * 8 + hw];
    float ws = __expf(lrelu(a_src[nd * 8 + hd] + ad_acc));   // self loop
    uint32_t gs = *(const uint32_t*)(g + (size_t)nd * 64 + lane32 * 2);
    float s = ws;
    float acc0 = ws * lo16f(gs), acc1 = ws * hi16f(gs);
    int jb = off[nd], je = off[nd + 1];
    int addrH = (tid & 32) * 4;        // byte addr of half-wave base lane
    int addrW = addrH + hd * 4;
    for (int j = jb; j < je; j += 4) {
        int cnt = je - j;              // uniform per half
        int jj = j + e4;
        int idx = srt[jj < je ? jj : (je - 1)];
        float w = __expf(lrelu(a_src[idx * 8 + hw] + ad_w));
        int wi = __builtin_bit_cast(int, w);
#pragma unroll
        for (int t = 0; t < 4; ++t) {
            int srcv = __builtin_amdgcn_ds_bpermute(addrH + t * 32, idx);
            int wvi  = __builtin_amdgcn_ds_bpermute(addrW + t * 32, wi);
            float wv = (t < cnt) ? __builtin_bit_cast(float, wvi) : 0.f;
            uint32_t gv = *(const uint32_t*)(g + (size_t)srcv * 64 + lane32 * 2);
            s += wv;
            acc0 += wv * lo16f(gv);
            acc1 += wv * hi16f(gv);
        }
    }
    float r = 1.f / (s + 1e-16f);
    float2 bv = *(const float2*)(bias + lane32 * 2);
    float p = pslope[0];
    float v0 = acc0 * r + bv.x; v0 = v0 >= 0.f ? v0 : p * v0;
    float v1 = acc1 * r + bv.y; v1 = v1 >= 0.f ? v1 : p * v1;
    if (node < N) *(uint32_t*)(hout + (size_t)node * 64 + lane32 * 2) = pack2(v0, v1);
}

// ---------------- layer 3 aggregation + head-mean + bias + log_softmax ----------------
__global__ __launch_bounds__(256) void agg3(const u16* __restrict__ g,
                                            const float* __restrict__ a_src, const float* __restrict__ a_dst,
                                            const int* __restrict__ off, const int* __restrict__ srt,
                                            const float* __restrict__ b3, float* __restrict__ out, int N) {
    int tid = threadIdx.x;
    int lane = tid & 63;
    int node = blockIdx.x * 4 + (tid >> 6);
    int nd = node < N ? node : N - 1;
    int hd = lane >> 3;       // head for accumulation (== e8 of weight layout)
    int hw = lane & 7;        // head for weight layout
    float ad_acc = a_dst[nd * 8 + hd];
    float ad_w   = a_dst[nd * 8 + hw];
    float ws = __expf(lrelu(a_src[nd * 8 + hd] + ad_acc));
    uint32_t gs = *(const uint32_t*)(g + (size_t)nd * 128 + lane * 2);
    float s = ws;
    float acc0 = ws * lo16f(gs), acc1 = ws * hi16f(gs);
    int jb = off[nd], je = off[nd + 1];
    int addrW = hd * 4;
    for (int j = jb; j < je; j += 8) {
        int cnt = je - j;
        int jj = j + hd;      // e8 == hd
        int idx = srt[jj < je ? jj : (je - 1)];
        float w = __expf(lrelu(a_src[idx * 8 + hw] + ad_w));
        int wi = __builtin_bit_cast(int, w);
#pragma unroll
        for (int t = 0; t < 8; ++t) {
            int srcv = __builtin_amdgcn_readlane(idx, t * 8);
            int wvi  = __builtin_amdgcn_ds_bpermute(addrW + t * 32, wi);
            float wv = (t < cnt) ? __builtin_bit_cast(float, wvi) : 0.f;
            uint32_t gv = *(const uint32_t*)(g + (size_t)srcv * 128 + lane * 2);
            s += wv;
            acc0 += wv * lo16f(gv);
            acc1 += wv * hi16f(gv);
        }
    }
    float r = 1.f / (s + 1e-16f);
    float v0 = acc0 * r, v1 = acc1 * r;
    v0 += __shfl_xor(v0, 8);  v1 += __shfl_xor(v1, 8);
    v0 += __shfl_xor(v0, 16); v1 += __shfl_xor(v1, 16);
    v0 += __shfl_xor(v0, 32); v1 += __shfl_xor(v1, 32);
    int c0 = (lane & 7) * 2;
    float2 bv = *(const float2*)(b3 + c0);
    float mean0 = v0 * 0.125f + bv.x, mean1 = v1 * 0.125f + bv.y;
    float m = fmaxf(mean0, mean1);
    m = fmaxf(m, __shfl_xor(m, 1)); m = fmaxf(m, __shfl_xor(m, 2)); m = fmaxf(m, __shfl_xor(m, 4));
    float se = __expf(mean0 - m) + __expf(mean1 - m);
    se += __shfl_xor(se, 1); se += __shfl_xor(se, 2); se += __shfl_xor(se, 4);
    float lg = __logf(se);
    if (node < N && lane < 8) {
        float2 o; o.x = mean0 - m - lg; o.y = mean1 - m - lg;
        *(float2*)(out + (size_t)node * 16 + c0) = o;
    }
}

// ---------------- launch ----------------
extern "C" void kernel_launch(void* const* d_in, const int* in_sizes, int n_in,
                              void* d_out, int out_size, void* d_ws, size_t ws_size,
                              hipStream_t stream) {
    (void)n_in; (void)out_size; (void)ws_size;
    const float* x  = (const float*)d_in[0];
    const int* ei   = (const int*)d_in[1];
    const float* W1 = (const float*)d_in[2];
    const float* as1 = (const float*)d_in[3];
    const float* ad1 = (const float*)d_in[4];
    const float* b1  = (const float*)d_in[5];
    const float* W2  = (const float*)d_in[6];
    const float* as2 = (const float*)d_in[7];
    const float* ad2 = (const float*)d_in[8];
    const float* b2  = (const float*)d_in[9];
    const float* W3  = (const float*)d_in[10];
    const float* as3 = (const float*)d_in[11];
    const float* ad3 = (const float*)d_in[12];
    const float* b3  = (const float*)d_in[13];
    const float* p1  = (const float*)d_in[14];
    const float* p2  = (const float*)d_in[15];
    const int N = in_sizes[0] / 256;
    const int E = in_sizes[1] / 2;

    char* ws = (char*)d_ws;
    size_t o = 0;
    auto alloc = [&](size_t bytes) { void* p = ws + o; o = (o + bytes + 255) & ~(size_t)255; return p; };
    int* deg    = (int*)alloc((size_t)N * 4);
    int* off    = (int*)alloc((size_t)(N + 1) * 4);
    int* cursor = (int*)alloc((size_t)N * 4);
    int* bsum   = (int*)alloc(4096);
    int* srt    = (int*)alloc((size_t)E * 4);
    u16* xb     = (u16*)alloc((size_t)N * 256 * 2);
    u16* g      = (u16*)alloc((size_t)N * 128 * 2);
    float* a_src = (float*)alloc((size_t)N * 8 * 4);
    float* a_dst = (float*)alloc((size_t)N * 8 * 4);
    u16* h1     = (u16*)alloc((size_t)N * 64 * 2);
    u16* h2     = (u16*)alloc((size_t)N * 64 * 2);

    (void)hipMemsetAsync(deg, 0, (size_t)N * 4, stream);
    int n4 = N * 256 / 4;
    k_cvt<<<(n4 + 255) / 256, 256, 0, stream>>>(x, xb, n4);
    int eb = (E + 255) / 256;
    k_count<<<eb, 256, 0, stream>>>(ei + E, deg, E);
    int nS = (N + 1 + 1023) / 1024;
    k_scanpart<<<nS, 1024, 0, stream>>>(deg, bsum, N + 1, N);
    k_scanbsum<<<1, 64, 0, stream>>>(bsum, nS);
    k_scanfinal<<<nS, 1024, 0, stream>>>(deg, bsum, off, cursor, N + 1, N);
    k_scatter<<<eb, 256, 0, stream>>>(ei, ei + E, cursor, srt, E);

    int nb64 = (N + 63) / 64;
    int nb4 = (N + 3) / 4;
    int nb8 = (N + 7) / 8;

    // layer 1: x[N,256] @ W1[256,64]
    gemm_k<<<dim3(nb64, 1), 256, 0, stream>>>(xb, 256, (const u16*)nullptr, 0, W1, 64, g, N);
    acomp8<<<nb4, 256, 0, stream>>>(g, as1, ad1, a_src, a_dst, N);
    agg12<<<nb8, 256, 0, stream>>>(g, a_src, a_dst, off, srt, b1, p1, h1, N);

    // layer 2: concat(x, h1)[N,320] @ W2[320,64]
    gemm_k<<<dim3(nb64, 1), 256, 0, stream>>>(xb, 256, h1, 64, W2, 64, g, N);
    acomp8<<<nb4, 256, 0, stream>>>(g, as2, ad2, a_src, a_dst, N);
    agg12<<<nb8, 256, 0, stream>>>(g, a_src, a_dst, off, srt, b2, p2, h2, N);

    // layer 3: h2[N,64] @ W3[64,128], mean over heads + log_softmax
    gemm_k<<<dim3(nb64, 2), 256, 0, stream>>>(h2, 64, (const u16*)nullptr, 0, W3, 128, g, N);
    acomp16<<<nb4, 256, 0, stream>>>(g, as3, ad3, a_src, a_dst, N);
    agg3<<<nb4, 256, 0, stream>>>(g, a_src, a_dst, off, srt, b3, (float*)d_out, N);
}

// Round 9
// 568.875 us; speedup vs baseline: 1.7505x; 1.2420x over previous
//
#include <hip/hip_runtime.h>
#include <hip/hip_bf16.h>
#include <stdint.h>

typedef unsigned short u16;
typedef __attribute__((ext_vector_type(8))) short short8;
typedef __attribute__((ext_vector_type(8))) __bf16 bf16x8;
typedef __attribute__((ext_vector_type(4))) float f32x4;
typedef __attribute__((ext_vector_type(4))) float fv4;

#define DEV static __device__ __forceinline__

DEV float bf2f(u16 u) { uint32_t i = ((uint32_t)u) << 16; float f; __builtin_memcpy(&f, &i, 4); return f; }
DEV u16 f2bf(float f) {
    uint32_t i; __builtin_memcpy(&i, &f, 4);
    uint32_t r = i + 0x7FFFu + ((i >> 16) & 1u);
    return (u16)(r >> 16);
}
DEV float lo16f(uint32_t u) { uint32_t i = u << 16; float f; __builtin_memcpy(&f, &i, 4); return f; }
DEV float hi16f(uint32_t u) { uint32_t i = u & 0xFFFF0000u; float f; __builtin_memcpy(&f, &i, 4); return f; }
DEV uint32_t pack2(float a, float b) { return (uint32_t)f2bf(a) | ((uint32_t)f2bf(b) << 16); }
DEV float lrelu(float x) { return x >= 0.f ? x : 0.2f * x; }

#define CHK 4096      // edges per partition block
#define BN2SH 10      // 1024 nodes per bucket
#define BN2 1024

// ---------------- x -> bf16 pre-convert ----------------
__global__ __launch_bounds__(256) void k_cvt(const float* __restrict__ in, u16* __restrict__ out, int n4) {
    int i = blockIdx.x * 256 + threadIdx.x;
    if (i < n4) {
        fv4 v = __builtin_nontemporal_load((const fv4*)in + i);
        ushort4 o;
        o.x = f2bf(v.x); o.y = f2bf(v.y); o.z = f2bf(v.z); o.w = f2bf(v.w);
        ((ushort4*)out)[i] = o;
    }
}

// ---------------- CSR build: atomic-free bucket partition ----------------
// pass 1: per-block histogram of dst buckets
__global__ __launch_bounds__(256) void k_hist(const int* __restrict__ dst, int* __restrict__ hist,
                                              int NBUK, int nbp, int E) {
    __shared__ int h[BN2];
    int tid = threadIdx.x;
    for (int i = tid; i < NBUK; i += 256) h[i] = 0;
    __syncthreads();
    int b0 = blockIdx.x * CHK;
    int jend = b0 + CHK < E ? b0 + CHK : E;
    for (int j = b0 + tid; j < jend; j += 256)
        atomicAdd(&h[dst[j] >> BN2SH], 1);
    __syncthreads();
    for (int i = tid; i < NBUK; i += 256) hist[i * nbp + blockIdx.x] = h[i];
}

__global__ void k_scanpart(const int* __restrict__ deg, int* __restrict__ bsum, int n) {
    __shared__ int buf[1024];
    int tid = threadIdx.x;
    int i = blockIdx.x * 1024 + tid;
    int v = (i < n) ? deg[i] : 0;
    buf[tid] = v; __syncthreads();
    for (int d = 512; d > 0; d >>= 1) {
        if (tid < d) buf[tid] += buf[tid + d];
        __syncthreads();
    }
    if (tid == 0) bsum[blockIdx.x] = buf[0];
}

__global__ void k_scanbsum(int* bsum, int nb) {
    if (threadIdx.x == 0) {
        int run = 0;
        for (int b = 0; b < nb; ++b) { int t = bsum[b]; bsum[b] = run; run += t; }
    }
}

__global__ void k_scanonly(const int* __restrict__ in, const int* __restrict__ bsum,
                           int* __restrict__ out, int n) {
    __shared__ int buf[1024];
    int tid = threadIdx.x;
    int i = blockIdx.x * 1024 + tid;
    int v = (i < n) ? in[i] : 0;
    buf[tid] = v; __syncthreads();
    for (int d = 1; d < 1024; d <<= 1) {
        int t = (tid >= d) ? buf[tid - d] : 0;
        __syncthreads();
        buf[tid] += t;
        __syncthreads();
    }
    if (i < n) out[i] = buf[tid] - v + bsum[blockIdx.x];
}

// pass 3: partition edges into bucket-contiguous staging via LDS cursors
__global__ __launch_bounds__(256) void k_part(const int* __restrict__ src, const int* __restrict__ dst,
                                              const int* __restrict__ scanned, int2* __restrict__ stage,
                                              int NBUK, int nbp, int E) {
    __shared__ int cur[BN2];
    int tid = threadIdx.x;
    for (int i = tid; i < NBUK; i += 256) cur[i] = scanned[i * nbp + blockIdx.x];
    __syncthreads();
    int b0 = blockIdx.x * CHK;
    int jend = b0 + CHK < E ? b0 + CHK : E;
    for (int j = b0 + tid; j < jend; j += 256) {
        int d = dst[j];
        int p = atomicAdd(&cur[d >> BN2SH], 1);
        stage[p] = make_int2(src[j], d);
    }
}

// level 2: exact CSR within each bucket (LDS-only atomics, coalesced/local writes)
__global__ __launch_bounds__(256) void k_csr(const int2* __restrict__ stage, const int* __restrict__ scanned,
                                             int* __restrict__ off, int* __restrict__ srt,
                                             int NBUK, int nbp, int N, int E) {
    __shared__ int deg[BN2];
    __shared__ int ex[BN2];
    __shared__ int tsum[256];
    int tid = threadIdx.x, b = blockIdx.x;
    int base = b << BN2SH;
    int s0 = scanned[b * nbp];
    int s1 = (b + 1 < NBUK) ? scanned[(b + 1) * nbp] : E;
    for (int i = tid; i < BN2; i += 256) deg[i] = 0;
    __syncthreads();
    for (int j = s0 + tid; j < s1; j += 256) atomicAdd(&deg[stage[j].y - base], 1);
    __syncthreads();
    int t4 = tid * 4;
    int d0 = deg[t4], d1 = deg[t4 + 1], d2 = deg[t4 + 2], d3 = deg[t4 + 3];
    int tot = d0 + d1 + d2 + d3;
    tsum[tid] = tot; __syncthreads();
    for (int d = 1; d < 256; d <<= 1) {
        int t = (tid >= d) ? tsum[tid - d] : 0;
        __syncthreads();
        tsum[tid] += t;
        __syncthreads();
    }
    int ebase = tsum[tid] - tot;
    ex[t4] = ebase; ex[t4 + 1] = ebase + d0; ex[t4 + 2] = ebase + d0 + d1; ex[t4 + 3] = ebase + d0 + d1 + d2;
    __syncthreads();
    for (int i = tid; i < BN2; i += 256) { int n = base + i; if (n < N) off[n] = s0 + ex[i]; }
    if (b == 0 && tid == 0) off[N] = E;
    __syncthreads();
    for (int j = s0 + tid; j < s1; j += 256) {
        int2 sd = stage[j];
        int p = atomicAdd(&ex[sd.y - base], 1);
        srt[s0 + p] = sd.x;
    }
}

// ---------------- GEMM: out[N,M](bf16) = concat(A1[N,K1],A2[N,K2])(bf16) @ W[K,M](f32) ----------------
__global__ __launch_bounds__(256) void gemm_k(const u16* __restrict__ A1, int K1,
                                              const u16* __restrict__ A2, int K2,
                                              const float* __restrict__ W, int M,
                                              u16* __restrict__ out, int N) {
    __shared__ u16 wt[64][328];
    __shared__ u16 As[64][40];
    const int K = K1 + K2;
    const int tid = threadIdx.x;
    const int n0 = blockIdx.x * 64;
    const int cb = blockIdx.y * 64;

    for (int idx = tid; idx < K * 64; idx += 256) {
        int k = idx >> 6, m = idx & 63;
        wt[m][k] = f2bf(W[(size_t)k * M + cb + m]);
    }

    const int wv = tid >> 6, lane = tid & 63;
    const int quad = lane >> 4, r = lane & 15;
    f32x4 acc[4];
#pragma unroll
    for (int ct = 0; ct < 4; ++ct) acc[ct] = (f32x4){0.f, 0.f, 0.f, 0.f};

    const int row = tid >> 2, seg = tid & 3;
    const int gl = n0 + row;

    for (int k0 = 0; k0 < K; k0 += 32) {
        int4 v = {0, 0, 0, 0};
        if (gl < N) {
            const u16* base = (k0 < K1) ? (A1 + (size_t)gl * K1 + k0)
                                        : (A2 + (size_t)gl * K2 + (k0 - K1));
            v = *(const int4*)(base + seg * 8);
        }
        *(int4*)&As[row][seg * 8] = v;
        __syncthreads();
        bf16x8 a = __builtin_bit_cast(bf16x8, *(const short8*)&As[wv * 16 + r][quad * 8]);
#pragma unroll
        for (int ct = 0; ct < 4; ++ct) {
            bf16x8 b = __builtin_bit_cast(bf16x8, *(const short8*)&wt[ct * 16 + r][k0 + quad * 8]);
            acc[ct] = __builtin_amdgcn_mfma_f32_16x16x32_bf16(a, b, acc[ct], 0, 0, 0);
        }
        __syncthreads();
    }

#pragma unroll
    for (int ct = 0; ct < 4; ++ct)
#pragma unroll
        for (int rg = 0; rg < 4; ++rg) {
            int grow = n0 + wv * 16 + quad * 4 + rg;
            if (grow < N) out[(size_t)grow * M + cb + ct * 16 + r] = f2bf(acc[ct][rg]);
        }
}

// ---------------- attention coefficients: a_src/a_dst [N,8] fp32 ----------------
__global__ __launch_bounds__(256) void acomp8(const u16* __restrict__ g,
                                              const float* __restrict__ ats, const float* __restrict__ atd,
                                              float* __restrict__ a_src, float* __restrict__ a_dst, int N) {
    int lane = threadIdx.x & 63;
    int node = blockIdx.x * 4 + (threadIdx.x >> 6);
    if (node >= N) return;
    float val = bf2f(g[(size_t)node * 64 + lane]);
    float ps = val * ats[lane];
    float pd = val * atd[lane];
#pragma unroll
    for (int d = 1; d < 8; d <<= 1) { ps += __shfl_xor(ps, d); pd += __shfl_xor(pd, d); }
    if ((lane & 7) == 0) {
        a_src[node * 8 + (lane >> 3)] = ps;
        a_dst[node * 8 + (lane >> 3)] = pd;
    }
}

__global__ __launch_bounds__(256) void acomp16(const u16* __restrict__ g,
                                               const float* __restrict__ ats, const float* __restrict__ atd,
                                               float* __restrict__ a_src, float* __restrict__ a_dst, int N) {
    int lane = threadIdx.x & 63;
    int node = blockIdx.x * 4 + (threadIdx.x >> 6);
    if (node >= N) return;
    float v0 = bf2f(g[(size_t)node * 128 + lane]);
    float v1 = bf2f(g[(size_t)node * 128 + lane + 64]);
    float ps0 = v0 * ats[lane],      pd0 = v0 * atd[lane];
    float ps1 = v1 * ats[lane + 64], pd1 = v1 * atd[lane + 64];
#pragma unroll
    for (int d = 1; d < 16; d <<= 1) {
        ps0 += __shfl_xor(ps0, d); pd0 += __shfl_xor(pd0, d);
        ps1 += __shfl_xor(ps1, d); pd1 += __shfl_xor(pd1, d);
    }
    if ((lane & 15) == 0) {
        int hd = lane >> 4;
        a_src[node * 8 + hd] = ps0;     a_dst[node * 8 + hd] = pd0;
        a_src[node * 8 + hd + 4] = ps1; a_dst[node * 8 + hd + 4] = pd1;
    }
}

// ---------------- layer 1/2 aggregation: 2 nodes/wave, 2 channels/lane ----------------
__global__ __launch_bounds__(256) void agg12(const u16* __restrict__ g,
                                             const float* __restrict__ a_src, const float* __restrict__ a_dst,
                                             const int* __restrict__ off, const int* __restrict__ srt,
                                             const float* __restrict__ bias, const float* __restrict__ pslope,
                                             u16* __restrict__ hout, int N) {
    int tid = threadIdx.x;
    int lane32 = tid & 31;
    int node = blockIdx.x * 8 + (tid >> 5);
    int nd = node < N ? node : N - 1;
    int hd = lane32 >> 2;          // head for accumulation layout
    int hw = lane32 & 7;           // head for weight-compute layout
    int e4 = lane32 >> 3;          // edge slot (0..3) for weight-compute layout
    float ad_acc = a_dst[nd * 8 + hd];
    float ad_w   = a_dst[nd * 8 + hw];
    float ws = __expf(lrelu(a_src[nd * 8 + hd] + ad_acc));   // self loop
    uint32_t gs = *(const uint32_t*)(g + (size_t)nd * 64 + lane32 * 2);
    float s = ws;
    float acc0 = ws * lo16f(gs), acc1 = ws * hi16f(gs);
    int jb = off[nd], je = off[nd + 1];
    int addrH = (tid & 32) * 4;        // byte addr of half-wave base lane
    int addrW = addrH + hd * 4;
    for (int j = jb; j < je; j += 4) {
        int cnt = je - j;              // uniform per half
        int jj = j + e4;
        int idx = srt[jj < je ? jj : (je - 1)];
        float w = __expf(lrelu(a_src[idx * 8 + hw] + ad_w));
        int wi = __builtin_bit_cast(int, w);
#pragma unroll
        for (int t = 0; t < 4; ++t) {
            int srcv = __builtin_amdgcn_ds_bpermute(addrH + t * 32, idx);
            int wvi  = __builtin_amdgcn_ds_bpermute(addrW + t * 32, wi);
            float wv = (t < cnt) ? __builtin_bit_cast(float, wvi) : 0.f;
            uint32_t gv = *(const uint32_t*)(g + (size_t)srcv * 64 + lane32 * 2);
            s += wv;
            acc0 += wv * lo16f(gv);
            acc1 += wv * hi16f(gv);
        }
    }
    float r = 1.f / (s + 1e-16f);
    float2 bv = *(const float2*)(bias + lane32 * 2);
    float p = pslope[0];
    float v0 = acc0 * r + bv.x; v0 = v0 >= 0.f ? v0 : p * v0;
    float v1 = acc1 * r + bv.y; v1 = v1 >= 0.f ? v1 : p * v1;
    if (node < N) *(uint32_t*)(hout + (size_t)node * 64 + lane32 * 2) = pack2(v0, v1);
}

// ---------------- layer 3 aggregation + head-mean + bias + log_softmax ----------------
__global__ __launch_bounds__(256) void agg3(const u16* __restrict__ g,
                                            const float* __restrict__ a_src, const float* __restrict__ a_dst,
                                            const int* __restrict__ off, const int* __restrict__ srt,
                                            const float* __restrict__ b3, float* __restrict__ out, int N) {
    int tid = threadIdx.x;
    int lane = tid & 63;
    int node = blockIdx.x * 4 + (tid >> 6);
    int nd = node < N ? node : N - 1;
    int hd = lane >> 3;       // head for accumulation (== e8 of weight layout)
    int hw = lane & 7;        // head for weight layout
    float ad_acc = a_dst[nd * 8 + hd];
    float ad_w   = a_dst[nd * 8 + hw];
    float ws = __expf(lrelu(a_src[nd * 8 + hd] + ad_acc));
    uint32_t gs = *(const uint32_t*)(g + (size_t)nd * 128 + lane * 2);
    float s = ws;
    float acc0 = ws * lo16f(gs), acc1 = ws * hi16f(gs);
    int jb = off[nd], je = off[nd + 1];
    int addrW = hd * 4;
    for (int j = jb; j < je; j += 8) {
        int cnt = je - j;
        int jj = j + hd;      // e8 == hd
        int idx = srt[jj < je ? jj : (je - 1)];
        float w = __expf(lrelu(a_src[idx * 8 + hw] + ad_w));
        int wi = __builtin_bit_cast(int, w);
#pragma unroll
        for (int t = 0; t < 8; ++t) {
            int srcv = __builtin_amdgcn_readlane(idx, t * 8);
            int wvi  = __builtin_amdgcn_ds_bpermute(addrW + t * 32, wi);
            float wv = (t < cnt) ? __builtin_bit_cast(float, wvi) : 0.f;
            uint32_t gv = *(const uint32_t*)(g + (size_t)srcv * 128 + lane * 2);
            s += wv;
            acc0 += wv * lo16f(gv);
            acc1 += wv * hi16f(gv);
        }
    }
    float r = 1.f / (s + 1e-16f);
    float v0 = acc0 * r, v1 = acc1 * r;
    v0 += __shfl_xor(v0, 8);  v1 += __shfl_xor(v1, 8);
    v0 += __shfl_xor(v0, 16); v1 += __shfl_xor(v1, 16);
    v0 += __shfl_xor(v0, 32); v1 += __shfl_xor(v1, 32);
    int c0 = (lane & 7) * 2;
    float2 bv = *(const float2*)(b3 + c0);
    float mean0 = v0 * 0.125f + bv.x, mean1 = v1 * 0.125f + bv.y;
    float m = fmaxf(mean0, mean1);
    m = fmaxf(m, __shfl_xor(m, 1)); m = fmaxf(m, __shfl_xor(m, 2)); m = fmaxf(m, __shfl_xor(m, 4));
    float se = __expf(mean0 - m) + __expf(mean1 - m);
    se += __shfl_xor(se, 1); se += __shfl_xor(se, 2); se += __shfl_xor(se, 4);
    float lg = __logf(se);
    if (node < N && lane < 8) {
        float2 o; o.x = mean0 - m - lg; o.y = mean1 - m - lg;
        *(float2*)(out + (size_t)node * 16 + c0) = o;
    }
}

// ---------------- launch ----------------
extern "C" void kernel_launch(void* const* d_in, const int* in_sizes, int n_in,
                              void* d_out, int out_size, void* d_ws, size_t ws_size,
                              hipStream_t stream) {
    (void)n_in; (void)out_size; (void)ws_size;
    const float* x  = (const float*)d_in[0];
    const int* ei   = (const int*)d_in[1];
    const float* W1 = (const float*)d_in[2];
    const float* as1 = (const float*)d_in[3];
    const float* ad1 = (const float*)d_in[4];
    const float* b1  = (const float*)d_in[5];
    const float* W2  = (const float*)d_in[6];
    const float* as2 = (const float*)d_in[7];
    const float* ad2 = (const float*)d_in[8];
    const float* b2  = (const float*)d_in[9];
    const float* W3  = (const float*)d_in[10];
    const float* as3 = (const float*)d_in[11];
    const float* ad3 = (const float*)d_in[12];
    const float* b3  = (const float*)d_in[13];
    const float* p1  = (const float*)d_in[14];
    const float* p2  = (const float*)d_in[15];
    const int N = in_sizes[0] / 256;
    const int E = in_sizes[1] / 2;
    const int NBUK = (N + BN2 - 1) >> BN2SH;
    const int nbp = (E + CHK - 1) / CHK;
    const int nsc = NBUK * nbp;

    char* ws = (char*)d_ws;
    size_t o = 0;
    auto alloc = [&](size_t bytes) { void* p = ws + o; o = (o + bytes + 255) & ~(size_t)255; return p; };
    int* off     = (int*)alloc((size_t)(N + 1) * 4);
    int* bsum    = (int*)alloc(4096);
    int* hist    = (int*)alloc((size_t)nsc * 4);
    int* scanned = (int*)alloc((size_t)nsc * 4);
    int* srt     = (int*)alloc((size_t)E * 4);
    int2* stage  = (int2*)alloc((size_t)E * 8);
    u16* xb      = (u16*)alloc((size_t)N * 256 * 2);
    u16* g       = (u16*)alloc((size_t)N * 128 * 2);
    float* a_src = (float*)alloc((size_t)N * 8 * 4);
    float* a_dst = (float*)alloc((size_t)N * 8 * 4);
    u16* h1      = (u16*)alloc((size_t)N * 64 * 2);
    u16* h2      = (u16*)alloc((size_t)N * 64 * 2);

    int n4 = N * 256 / 4;
    k_cvt<<<(n4 + 255) / 256, 256, 0, stream>>>(x, xb, n4);

    // CSR build (atomic-free)
    k_hist<<<nbp, 256, 0, stream>>>(ei + E, hist, NBUK, nbp, E);
    int nS = (nsc + 1023) / 1024;
    k_scanpart<<<nS, 1024, 0, stream>>>(hist, bsum, nsc);
    k_scanbsum<<<1, 64, 0, stream>>>(bsum, nS);
    k_scanonly<<<nS, 1024, 0, stream>>>(hist, bsum, scanned, nsc);
    k_part<<<nbp, 256, 0, stream>>>(ei, ei + E, scanned, stage, NBUK, nbp, E);
    k_csr<<<NBUK, 256, 0, stream>>>(stage, scanned, off, srt, NBUK, nbp, N, E);

    int nb64 = (N + 63) / 64;
    int nb4 = (N + 3) / 4;
    int nb8 = (N + 7) / 8;

    // layer 1: x[N,256] @ W1[256,64]
    gemm_k<<<dim3(nb64, 1), 256, 0, stream>>>(xb, 256, (const u16*)nullptr, 0, W1, 64, g, N);
    acomp8<<<nb4, 256, 0, stream>>>(g, as1, ad1, a_src, a_dst, N);
    agg12<<<nb8, 256, 0, stream>>>(g, a_src, a_dst, off, srt, b1, p1, h1, N);

    // layer 2: concat(x, h1)[N,320] @ W2[320,64]
    gemm_k<<<dim3(nb64, 1), 256, 0, stream>>>(xb, 256, h1, 64, W2, 64, g, N);
    acomp8<<<nb4, 256, 0, stream>>>(g, as2, ad2, a_src, a_dst, N);
    agg12<<<nb8, 256, 0, stream>>>(g, a_src, a_dst, off, srt, b2, p2, h2, N);

    // layer 3: h2[N,64] @ W3[64,128], mean over heads + log_softmax
    gemm_k<<<dim3(nb64, 2), 256, 0, stream>>>(h2, 64, (const u16*)nullptr, 0, W3, 128, g, N);
    acomp16<<<nb4, 256, 0, stream>>>(g, as3, ad3, a_src, a_dst, N);
    agg3<<<nb4, 256, 0, stream>>>(g, a_src, a_dst, off, srt, b3, (float*)d_out, N);
}